// Round 2
// baseline (202.973 us; speedup 1.0000x reference)
//
#include <hip/hip_runtime.h>
#include <hip/hip_bf16.h>

// Elementwise over B=8388608 rows of X:(B,4) f32 -> out:(B,2) f32.
// Memory-bound: 128 MiB in + 64 MiB out -> ~30 us at 6.75 TB/s achieved.
// Native hw transcendentals (v_sin_f32/v_cos_f32): abs err ~2e-4 after
// amplification, threshold is 0.246 -- plenty of headroom.

__global__ __launch_bounds__(256) void cgp_kernel(const float4* __restrict__ X,
                                                  const float* __restrict__ ephs,
                                                  float2* __restrict__ out,
                                                  int B) {
    int i = blockIdx.x * blockDim.x + threadIdx.x;
    if (i >= B) return;

    const float c0 = ephs[0];
    const float c1 = ephs[1];

    float4 x = X[i];  // 16B/lane coalesced

    float n4 = x.x * x.y;
    float n5 = __sinf(n4 + c0);          // v_sin_f32 path
    float n6 = x.z * x.w;
    float n7 = fmaf(n5, n6, __sinf(x.z));
    float n8 = fmaf(__cosf(n7), c1, x.x);

    out[i] = make_float2(n7, n8);        // 8B/lane coalesced
}

extern "C" void kernel_launch(void* const* d_in, const int* in_sizes, int n_in,
                              void* d_out, int out_size, void* d_ws, size_t ws_size,
                              hipStream_t stream) {
    const float4* X  = (const float4*)d_in[0];
    const float* eph = (const float*)d_in[1];
    float2* out      = (float2*)d_out;
    int B = in_sizes[0] / 4;  // 8388608

    int block = 256;
    int grid = (B + block - 1) / block;  // 32768 blocks
    cgp_kernel<<<grid, block, 0, stream>>>(X, eph, out, B);
}